// Round 10
// baseline (440.566 us; speedup 1.0000x reference)
//
#include <hip/hip_runtime.h>
#include <math.h>

#define DD 128          // node embedding dim
#define RR 1024         // root nodes
#define TT 4            // trunk types; encoder TT is the output autoencoder
#define LL 64           // levels
#define MM 2048         // nodes per level
#define NBK 16          // nodes per chunk (one MFMA M-tile)
#define PAD16 (MM + 5*NBK)   // 2128 padded slots per level
#define CH (PAD16/NBK)       // 133 chunks per level == grid of persistent kernel

typedef __attribute__((ext_vector_type(8))) short short8v;   // 8 bf16 (4 VGPRs)
typedef __attribute__((ext_vector_type(4))) float f32x4;

static __device__ __forceinline__ unsigned short f2bf(float f) {
    unsigned u = __float_as_uint(f);
    unsigned r = (u + 0x7fffu + ((u >> 16) & 1u)) >> 16;   // RNE
    return (unsigned short)r;
}

// A&S 7.1.26 erf (|err| < 1.5e-7), branchless
static __device__ __forceinline__ float gelu_f(float h) {
    float x  = h * 0.70710678118654752f;
    float ax = fabsf(x);
    float t  = __builtin_amdgcn_rcpf(fmaf(0.3275911f, ax, 1.0f));
    float p  = fmaf(t, 1.061405429f, -1.453152027f);
    p = fmaf(p, t, 1.421413741f);
    p = fmaf(p, t, -0.284496736f);
    p = fmaf(p, t, 0.254829592f);
    p = p * t;
    float er = 1.0f - p * __expf(-ax * ax);
    er = copysignf(er, x);
    return 0.5f * h * (1.0f + er);
}

// ---------------------------------------------------------------------------
// Fused prep: [0,64) build order+chunkof | [64,304) convert weights |
// [304,336) copy roots | 336 zero flags.   One dispatch.
// ---------------------------------------------------------------------------
__global__ __launch_bounds__(256) void prep_all(
    const float* __restrict__ root, const float* __restrict__ W1,
    const float* __restrict__ W2, const int* __restrict__ types,
    float* __restrict__ buf,
    unsigned short* __restrict__ W1F, unsigned short* __restrict__ W2F,
    unsigned short* __restrict__ order, unsigned char* __restrict__ chunkof,
    unsigned int* __restrict__ flags)
{
    int bid = blockIdx.x, tid = threadIdx.x;
    if (bid < LL) {
        int l = bid;
        __shared__ int cnt[5], cur[5];
        if (tid < 5) cnt[tid] = 0;
        __syncthreads();
        for (int s = tid; s < PAD16; s += 256) order[l*PAD16 + s] = 0xFFFFu;
        for (int m = tid; m < MM; m += 256) {
            int t = types[l*MM + m];
            int e = (t >= TT) ? TT : t;
            atomicAdd(&cnt[e], 1);
        }
        __syncthreads();
        if (tid == 0) {
            int off = 0;
            for (int e = 0; e < 5; e++) { cur[e] = off; off += ((cnt[e] + NBK - 1)/NBK)*NBK; }
        }
        __syncthreads();
        for (int m = tid; m < MM; m += 256) {
            int t = types[l*MM + m];
            int e = (t >= TT) ? TT : t;
            int pos = atomicAdd(&cur[e], 1);
            order[l*PAD16 + pos] = (unsigned short)m;
            chunkof[l*MM + m] = (unsigned char)(pos >> 4);
        }
    } else if (bid < LL + 240) {
        int t0 = (bid - LL)*256 + tid;
        if (t0 < 5*16*8*64) {
            int lane = t0 & 63;
            int kk = (t0 >> 6) & 7;
            int nt = (t0 >> 9) & 15;
            int e  = t0 >> 13;
            int n  = nt*16 + (lane & 15);
            int k0 = kk*32 + (lane >> 4)*8;
            unsigned short v[8];
            #pragma unroll
            for (int j = 0; j < 8; j++) v[j] = f2bf(W1[(e*256 + k0 + j)*256 + n]);
            *(short8v*)&W1F[t0*8] = *(short8v*)v;
        } else {
            int t = t0 - 5*16*8*64;   // < 20480
            int lane = t & 63;
            int kk = (t >> 6) & 7;
            int nt = (t >> 9) & 7;
            int e  = t >> 12;
            int n  = nt*16 + (lane & 15);
            int k0 = kk*32 + (lane >> 4)*8;
            unsigned short v[8];
            #pragma unroll
            for (int j = 0; j < 8; j++) v[j] = f2bf(W2[(e*256 + k0 + j)*128 + n]);
            *(short8v*)&W2F[t*8] = *(short8v*)v;
        }
    } else if (bid < LL + 240 + 32) {
        int idx = (bid - (LL + 240))*256 + tid;   // 0..8191
        const f32x4* r4 = (const f32x4*)root;
        f32x4* o4 = (f32x4*)buf;
        #pragma unroll
        for (int q = 0; q < 4; q++) o4[idx*4 + q] = r4[idx*4 + q];
    } else {
        for (int i = tid; i < LL*CH; i += 256) flags[i] = 0u;
    }
}

// ---------------------------------------------------------------------------
// Persistent dataflow kernel: 133 WGs x 256 threads. WG g owns chunk g of every
// level. ALL flag traffic is funneled through 32 checker lanes (wave 0) which
// publish readiness bytes in LDS; gather threads only read LDS. Producer
// protocol (validated r7-r9): sc1 result stores -> per-wave vmcnt(0) drain ->
// LDS arrive counter -> 4th wave publishes sc1 flag. Row loads stay cached
// (flag-gated: no stale L2 line can exist).
// ---------------------------------------------------------------------------
__global__ __launch_bounds__(256, 1) void persist_mfma(
    const unsigned short* __restrict__ W1F, const unsigned short* __restrict__ W2F,
    const float* __restrict__ b1, const float* __restrict__ b2,
    const float* __restrict__ slots, const int* __restrict__ par,
    const int* __restrict__ types, const unsigned short* __restrict__ order,
    const unsigned char* __restrict__ chunkof,
    float* __restrict__ buf, unsigned int* __restrict__ flags)
{
    __shared__ int4 descs[LL][NBK];            // {node, p0, p1(~slot if out), etype}
    __shared__ int2 descs2[LL][NBK];           // producer flag idx per parent (-1 ready)
    __shared__ int ech[LL];
    __shared__ unsigned short axFA[8*64*8];    // A-frags of x, 8 KB
    __shared__ unsigned short axFB[8*64*8];    // double buffer, 8 KB
    __shared__ unsigned short hxF[8*64*8];     // A-frags of h, 8 KB
    __shared__ int wcnt[2];                    // per-level wave-arrive counters
    __shared__ unsigned char rdyb[2][32];      // readiness bytes, (m,side) pairs

    int tid = threadIdx.x;
    int wg  = blockIdx.x;

    // ---- prologue: resolve all levels' descriptors + producer flags ----
    for (int i = tid; i < LL*NBK; i += 256) {
        int l = i >> 4, s = i & 15;
        unsigned short o = order[l*PAD16 + wg*NBK + s];
        int4 d; int2 d2 = make_int2(-1, -1);
        if (o == 0xFFFFu) {
            d = make_int4(-1, 0, 0, -1);
        } else {
            int gi = l*MM + (int)o;
            int t = types[gi];
            int e = (t >= TT) ? TT : t;
            int p0 = par[2*gi];
            int p1 = (t >= TT) ? ~(t - TT) : par[2*gi + 1];
            d = make_int4((int)o, p0, p1, e);
            if (p0 >= RR) d2.x = ((p0 - RR) >> 11)*CH + (int)chunkof[p0 - RR];
            if (p1 >= RR) d2.y = ((p1 - RR) >> 11)*CH + (int)chunkof[p1 - RR];
        }
        descs[l][s] = d;
        descs2[l][s] = d2;
    }
    if (tid == 0) { wcnt[0] = 0; wcnt[1] = 0; }
    __syncthreads();
    for (int i = tid; i < LL; i += 256) ech[i] = descs[i][0].w;
    __syncthreads();

    int w  = tid >> 6;    // wave 0..3
    int lq = tid & 63;    // lane
    int m_own  = tid >> 4;   // row this thread gathers
    int seg_own = tid & 15;  // 16-float segment

    // resolve this thread's gather source for level l1 (no flag loads here)
    #define RESOLVE(l1, S, PR, P) {                                            \
        int4 d_ = descs[l1][m_own];                                            \
        if (d_.x < 0) { P = true; S = nullptr; PR = -1; }                      \
        else {                                                                 \
            P = false;                                                         \
            int2 d2_ = descs2[l1][m_own];                                      \
            if (seg_own < 8)  { S = buf + (size_t)d_.y*DD + seg_own*16;        \
                                PR = (d2_.x >= 0) ? m_own*2 : -1; }            \
            else if (d_.z < 0){ S = slots + (size_t)(~d_.z)*DD + (seg_own-8)*16; PR = -1; } \
            else              { S = buf + (size_t)d_.z*DD + (seg_own-8)*16;    \
                                PR = (d2_.y >= 0) ? m_own*2 + 1 : -1; }        \
        } }

    #define WRITE_FRAGS(AXT, V0, V1, V2, V3) {                                 \
        unsigned short tA_[8], tB_[8];                                         \
        _Pragma("unroll")                                                      \
        for (int j = 0; j < 4; j++) {                                          \
            tA_[j]   = f2bf(V0[j]); tA_[4+j] = f2bf(V1[j]);                    \
            tB_[j]   = f2bf(V2[j]); tB_[4+j] = f2bf(V3[j]);                    \
        }                                                                      \
        int k_ = seg_own*16;                                                   \
        int kk_ = k_ >> 5, ln_ = m_own + 16*((k_ >> 3) & 3);                   \
        *(short8v*)&AXT[(kk_*64 + ln_)*8] = *(short8v*)tA_;                    \
        k_ += 8; kk_ = k_ >> 5; ln_ = m_own + 16*((k_ >> 3) & 3);              \
        *(short8v*)&AXT[(kk_*64 + ln_)*8] = *(short8v*)tB_;                    \
    }

    // checker helper: flag index for pair `tid` at level l1
    #define CHK_FI(l1) ((tid & 1) ? descs2[l1][tid >> 1].y : descs2[l1][tid >> 1].x)

    // ---- level-0 gather (roots/slots: always ready) ----
    {
        const float* src; int pr; bool pad;
        RESOLVE(0, src, pr, pad);
        f32x4 z = (f32x4){0.f,0.f,0.f,0.f};
        f32x4 v0 = z, v1 = z, v2 = z, v3 = z;
        if (!pad) {
            const f32x4* s4 = (const f32x4*)src;
            v0 = s4[0]; v1 = s4[1]; v2 = s4[2]; v3 = s4[3];
        }
        WRITE_FRAGS(axFA, v0, v1, v2, v3);
    }
    // ---- prologue: readiness snapshot for level 1 (checkers only) ----
    if (tid < 32) {
        int fi_ = CHK_FI(1);
        unsigned char r = 1;
        if (fi_ >= 0)
            r = (__hip_atomic_load(&flags[fi_], __ATOMIC_RELAXED,
                                   __HIP_MEMORY_SCOPE_AGENT) != 0u) ? 1 : 0;
        rdyb[1][tid] = r;
    }
    // per-thread gather carry for level 1
    const float* srcC = nullptr; int pairC = -1; bool padC = true;
    if (LL > 1) RESOLVE(1, srcC, pairC, padC);
    __syncthreads();

    unsigned short* axc = axFA;
    unsigned short* axn = axFB;

    for (int l = 0; l < LL; l++) {
        bool havN = (l + 1 < LL);
        int cur = (l + 1) & 1;     // readiness buffer for level l+1
        int nxt = l & 1;           // readiness buffer for level l+2
        if (tid == 0) wcnt[(l + 1) & 1] = 0;   // reset other-parity arrive counter

        // ---- phase A: row loads for LDS-confirmed-ready parents ----
        bool pend = false;
        f32x4 z = (f32x4){0.f,0.f,0.f,0.f};
        f32x4 v0 = z, v1 = z, v2 = z, v3 = z;
        if (havN && !padC) {
            bool ready = (pairC < 0) || (rdyb[cur][pairC] != 0);
            if (ready) {
                asm volatile("" ::: "memory");
                const f32x4* s4 = (const f32x4*)srcC;
                v0 = s4[0]; v1 = s4[1]; v2 = s4[2]; v3 = s4[3];
            } else {
                pend = true;
            }
        }
        // checkers: issue ONE fresh flag load per still-pending pair
        unsigned fv2 = 0; int fiChk = -1;
        if (havN && tid < 32) {
            int fi_ = CHK_FI(l + 1);
            if (fi_ >= 0 && rdyb[cur][tid] == 0) {
                fiChk = fi_;
                fv2 = __hip_atomic_load(&flags[fi_], __ATOMIC_RELAXED,
                                        __HIP_MEMORY_SCOPE_AGENT);
            }
        }
        __builtin_amdgcn_sched_barrier(0);   // pin: loads issued before compute

        int e = ech[l];
        if (e >= 0) {
            // ---- layer 1: H = GELU(X @ W1[e] + b1[e]) ----
            f32x4 acc[4];
            #pragma unroll
            for (int c = 0; c < 4; c++) {
                float bv = b1[e*256 + w*64 + c*16 + (lq & 15)];
                acc[c] = (f32x4){bv, bv, bv, bv};
            }
            {
                const short8v* Ab = (const short8v*)axc;
                #pragma unroll
                for (int kk = 0; kk < 8; kk++) {
                    short8v a = Ab[kk*64 + lq];
                    #pragma unroll
                    for (int c = 0; c < 4; c++) {
                        int nt = w*4 + c;
                        short8v bfr = *(const short8v*)&W1F[(((e*16 + nt)*8 + kk)*64 + lq)*8];
                        acc[c] = __builtin_amdgcn_mfma_f32_16x16x32_bf16(a, bfr, acc[c], 0, 0, 0);
                    }
                }
            }
            // ---- mid-check: consume checker re-loads, issue late row loads ----
            if (fiChk >= 0 && fv2 != 0u) rdyb[cur][tid] = 1;
            if (pend && *(volatile unsigned char*)&rdyb[cur][pairC]) {
                asm volatile("" ::: "memory");
                const f32x4* s4 = (const f32x4*)srcC;
                v0 = s4[0]; v1 = s4[1]; v2 = s4[2]; v3 = s4[3];
                pend = false;
            }
            __builtin_amdgcn_sched_barrier(0);

            #pragma unroll
            for (int c = 0; c < 4; c++) {
                int nh = w*64 + c*16 + (lq & 15);
                int kk2 = nh >> 5;
                int jj  = nh & 7;
                int lhi = 16*((nh >> 3) & 3);
                #pragma unroll
                for (int r = 0; r < 4; r++) {
                    int m = (lq >> 4)*4 + r;
                    hxF[(kk2*64 + (m + lhi))*8 + jj] = f2bf(gelu_f(acc[c][r]));
                }
            }
            __syncthreads();

            // ---- layer 2: OUT = H @ W2[e] + b2[e] ----
            f32x4 acc2[2];
            #pragma unroll
            for (int c = 0; c < 2; c++) {
                float bv = b2[e*128 + w*32 + c*16 + (lq & 15)];
                acc2[c] = (f32x4){bv, bv, bv, bv};
            }
            {
                const short8v* Hb = (const short8v*)hxF;
                #pragma unroll
                for (int kk = 0; kk < 8; kk++) {
                    short8v a = Hb[kk*64 + lq];
                    #pragma unroll
                    for (int c = 0; c < 2; c++) {
                        int nt = w*2 + c;
                        short8v bfr = *(const short8v*)&W2F[(((e*8 + nt)*8 + kk)*64 + lq)*8];
                        acc2[c] = __builtin_amdgcn_mfma_f32_16x16x32_bf16(a, bfr, acc2[c], 0, 0, 0);
                    }
                }
            }
            // result rows: sc1 write-through to the coherence point
            int baserow = RR + l*MM;
            #pragma unroll
            for (int r = 0; r < 4; r++) {
                int m = (lq >> 4)*4 + r;
                int node = descs[l][m].x;
                if (node >= 0) {
                    #pragma unroll
                    for (int c = 0; c < 2; c++) {
                        int n = w*32 + c*16 + (lq & 15);
                        __hip_atomic_store(&buf[(size_t)(baserow + node)*DD + n], acc2[c][r],
                                           __ATOMIC_RELAXED, __HIP_MEMORY_SCOPE_AGENT);
                    }
                }
            }
            // per-wave drain, LDS arrive, 4th wave publishes (no barrier)
            asm volatile("s_waitcnt vmcnt(0)" ::: "memory");
            if ((tid & 63) == 0) {
                int old = atomicAdd(&wcnt[l & 1], 1);
                if (old == 3)
                    __hip_atomic_store(&flags[l*CH + wg], 1u, __ATOMIC_RELAXED,
                                       __HIP_MEMORY_SCOPE_AGENT);
            }
        }

        // ---- snapshot issue for level l+2 (checkers; consumed at bottom) ----
        unsigned fvN = 1u; int fiNN = -1;
        if (l + 2 < LL && tid < 32) {
            fiNN = CHK_FI(l + 2);
            if (fiNN >= 0)
                fvN = __hip_atomic_load(&flags[fiNN], __ATOMIC_RELAXED,
                                        __HIP_MEMORY_SCOPE_AGENT);
        }

        // ---- phase B: checker spins on genuine stragglers; data spins on LDS ----
        if (havN) {
            if (tid < 32) {
                int fi_ = CHK_FI(l + 1);
                if (fi_ >= 0 && rdyb[cur][tid] == 0) {
                    while (__hip_atomic_load(&flags[fi_], __ATOMIC_RELAXED,
                                             __HIP_MEMORY_SCOPE_AGENT) == 0u)
                        __builtin_amdgcn_s_sleep(1);
                    rdyb[cur][tid] = 1;
                }
            }
            if (pend) {
                while (*(volatile unsigned char*)&rdyb[cur][pairC] == 0)
                    __builtin_amdgcn_s_sleep(1);
                asm volatile("" ::: "memory");
                const f32x4* s4 = (const f32x4*)srcC;
                v0 = s4[0]; v1 = s4[1]; v2 = s4[2]; v3 = s4[3];
            }
            WRITE_FRAGS(axn, v0, v1, v2, v3);
        }

        // ---- write snapshot, resolve per-thread carry for l+2 ----
        if (l + 2 < LL && tid < 32)
            rdyb[nxt][tid] = (fiNN < 0) ? 1 : ((fvN != 0u) ? 1 : 0);
        const float* srcN = nullptr; int pairN = -1; bool padN = true;
        if (l + 2 < LL) RESOLVE(l+2, srcN, pairN, padN);
        __syncthreads();
        unsigned short* t2 = axc; axc = axn; axn = t2;
        srcC = srcN; pairC = pairN; padC = padN;
    }
}

extern "C" void kernel_launch(void* const* d_in, const int* in_sizes, int n_in,
                              void* d_out, int out_size, void* d_ws, size_t ws_size,
                              hipStream_t stream) {
    const float* root  = (const float*)d_in[0];   // (1024, 128)
    const float* W1    = (const float*)d_in[1];   // (5, 256, 256)
    const float* b1    = (const float*)d_in[2];   // (5, 256)
    const float* W2    = (const float*)d_in[3];   // (5, 256, 128)
    const float* b2    = (const float*)d_in[4];   // (5, 128)
    const float* slots = (const float*)d_in[5];   // (256, 128)
    const int*   par   = (const int*)d_in[6];     // (131072, 2)
    const int*   typ   = (const int*)d_in[7];     // (131072,)
    float* out = (float*)d_out;                   // (132096, 128)

    unsigned short* W1F     = (unsigned short*)d_ws;          // 327680 shorts
    unsigned short* W2F     = W1F + 5*16*8*64*8;              // 163840 shorts
    unsigned short* order   = W2F + 5*8*8*64*8;               // 64*2128 shorts
    unsigned char*  chunkof = (unsigned char*)(order + LL*PAD16);  // 131072 B
    unsigned int*   flags   = (unsigned int*)(chunkof + LL*MM);    // 8512 u32

    // single fused prep dispatch (order/chunkof, weights, roots, flags)
    prep_all<<<LL + 240 + 32 + 1, 256, 0, stream>>>(root, W1, W2, typ, out,
                                                    W1F, W2F, order, chunkof, flags);

    // persistent dataflow sweep (co-residency guaranteed by cooperative launch)
    void* args[] = { (void*)&W1F, (void*)&W2F, (void*)&b1, (void*)&b2,
                     (void*)&slots, (void*)&par, (void*)&typ, (void*)&order,
                     (void*)&chunkof, (void*)&out, (void*)&flags };
    hipLaunchCooperativeKernel((const void*)persist_mfma, dim3(CH), dim3(256),
                               args, 0, stream);
}

// Round 11
// 392.231 us; speedup vs baseline: 1.1232x; 1.1232x over previous
//
#include <hip/hip_runtime.h>
#include <math.h>

#define DD 128          // node embedding dim
#define RR 1024         // root nodes
#define TT 4            // trunk types; encoder TT is the output autoencoder
#define LL 64           // levels
#define MM 2048         // nodes per level
#define NBK 16          // nodes per chunk (one MFMA M-tile)
#define NBUCK 10        // 5 encoder types x {old-parents, recent-parents}
#define PAD16 (MM + NBUCK*NBK)   // 2208 padded slots per level
#define CH (PAD16/NBK)           // 138 chunks per level == grid of persistent kernel

typedef __attribute__((ext_vector_type(8))) short short8v;   // 8 bf16 (4 VGPRs)
typedef __attribute__((ext_vector_type(4))) float f32x4;

static __device__ __forceinline__ unsigned short f2bf(float f) {
    unsigned u = __float_as_uint(f);
    unsigned r = (u + 0x7fffu + ((u >> 16) & 1u)) >> 16;   // RNE
    return (unsigned short)r;
}

// A&S 7.1.26 erf (|err| < 1.5e-7), branchless
static __device__ __forceinline__ float gelu_f(float h) {
    float x  = h * 0.70710678118654752f;
    float ax = fabsf(x);
    float t  = __builtin_amdgcn_rcpf(fmaf(0.3275911f, ax, 1.0f));
    float p  = fmaf(t, 1.061405429f, -1.453152027f);
    p = fmaf(p, t, 1.421413741f);
    p = fmaf(p, t, -0.284496736f);
    p = fmaf(p, t, 0.254829592f);
    p = p * t;
    float er = 1.0f - p * __expf(-ax * ax);
    er = copysignf(er, x);
    return 0.5f * h * (1.0f + er);
}

// ---------------------------------------------------------------------------
// Fused prep: [0,64) build order+chunkof | [64,304) convert weights |
// [304,336) copy roots | 336 zero flags.   One dispatch.
// Bucketing: (encoder e, recency) -> nodes with NO level-(l-1) parent ("sail")
// pack into low chunks; nodes with a just-produced parent ("gate") into high
// chunks. Sail chunks never wait on the previous level -> the per-level
// producer->consumer handoff latency hits only the few gate chunks.
// ---------------------------------------------------------------------------
__global__ __launch_bounds__(256) void prep_all(
    const float* __restrict__ root, const float* __restrict__ W1,
    const float* __restrict__ W2, const int* __restrict__ types,
    const int* __restrict__ par,
    float* __restrict__ buf,
    unsigned short* __restrict__ W1F, unsigned short* __restrict__ W2F,
    unsigned short* __restrict__ order, unsigned char* __restrict__ chunkof,
    unsigned int* __restrict__ flags)
{
    int bid = blockIdx.x, tid = threadIdx.x;
    if (bid < LL) {
        int l = bid;
        __shared__ int cnt[NBUCK], cur[NBUCK];
        if (tid < NBUCK) cnt[tid] = 0;
        __syncthreads();
        for (int s = tid; s < PAD16; s += 256) order[l*PAD16 + s] = 0xFFFFu;
        int thr = RR + (l-1)*MM;    // parents >= thr come from level l-1
        for (int m = tid; m < MM; m += 256) {
            int gi = l*MM + m;
            int t = types[gi];
            int e = (t >= TT) ? TT : t;
            int p0 = par[2*gi];
            bool rec = (p0 >= RR) && (p0 >= thr);
            if (t < TT) {
                int p1 = par[2*gi + 1];
                rec = rec || ((p1 >= RR) && (p1 >= thr));
            }
            atomicAdd(&cnt[e*2 + (rec ? 1 : 0)], 1);
        }
        __syncthreads();
        if (tid == 0) {
            int off = 0;
            for (int b = 0; b < NBUCK; b++) { cur[b] = off; off += ((cnt[b] + NBK - 1)/NBK)*NBK; }
        }
        __syncthreads();
        for (int m = tid; m < MM; m += 256) {
            int gi = l*MM + m;
            int t = types[gi];
            int e = (t >= TT) ? TT : t;
            int p0 = par[2*gi];
            bool rec = (p0 >= RR) && (p0 >= thr);
            if (t < TT) {
                int p1 = par[2*gi + 1];
                rec = rec || ((p1 >= RR) && (p1 >= thr));
            }
            int pos = atomicAdd(&cur[e*2 + (rec ? 1 : 0)], 1);
            order[l*PAD16 + pos] = (unsigned short)m;
            chunkof[l*MM + m] = (unsigned char)(pos >> 4);
        }
    } else if (bid < LL + 240) {
        int t0 = (bid - LL)*256 + tid;
        if (t0 < 5*16*8*64) {
            int lane = t0 & 63;
            int kk = (t0 >> 6) & 7;
            int nt = (t0 >> 9) & 15;
            int e  = t0 >> 13;
            int n  = nt*16 + (lane & 15);
            int k0 = kk*32 + (lane >> 4)*8;
            unsigned short v[8];
            #pragma unroll
            for (int j = 0; j < 8; j++) v[j] = f2bf(W1[(e*256 + k0 + j)*256 + n]);
            *(short8v*)&W1F[t0*8] = *(short8v*)v;
        } else {
            int t = t0 - 5*16*8*64;   // < 20480
            int lane = t & 63;
            int kk = (t >> 6) & 7;
            int nt = (t >> 9) & 7;
            int e  = t >> 12;
            int n  = nt*16 + (lane & 15);
            int k0 = kk*32 + (lane >> 4)*8;
            unsigned short v[8];
            #pragma unroll
            for (int j = 0; j < 8; j++) v[j] = f2bf(W2[(e*256 + k0 + j)*128 + n]);
            *(short8v*)&W2F[t*8] = *(short8v*)v;
        }
    } else if (bid < LL + 240 + 32) {
        int idx = (bid - (LL + 240))*256 + tid;   // 0..8191
        const f32x4* r4 = (const f32x4*)root;
        f32x4* o4 = (f32x4*)buf;
        #pragma unroll
        for (int q = 0; q < 4; q++) o4[idx*4 + q] = r4[idx*4 + q];
    } else {
        for (int i = tid; i < LL*CH; i += 256) flags[i] = 0u;
    }
}

// ---------------------------------------------------------------------------
// Persistent dataflow kernel: CH WGs x 256 threads. WG g owns chunk g of every
// level. ALL flag traffic is funneled through 32 checker lanes (wave 0) which
// publish readiness bytes in LDS; gather threads only read LDS. Producer
// protocol (validated r7-r10): sc1 result stores -> per-wave vmcnt(0) drain ->
// LDS arrive counter -> 4th wave publishes sc1 flag. Row loads stay cached
// (flag-gated: no stale L2 line can exist).
// ---------------------------------------------------------------------------
__global__ __launch_bounds__(256, 1) void persist_mfma(
    const unsigned short* __restrict__ W1F, const unsigned short* __restrict__ W2F,
    const float* __restrict__ b1, const float* __restrict__ b2,
    const float* __restrict__ slots, const int* __restrict__ par,
    const int* __restrict__ types, const unsigned short* __restrict__ order,
    const unsigned char* __restrict__ chunkof,
    float* __restrict__ buf, unsigned int* __restrict__ flags)
{
    __shared__ int4 descs[LL][NBK];            // {node, p0, p1(~slot if out), etype}
    __shared__ int2 descs2[LL][NBK];           // producer flag idx per parent (-1 ready)
    __shared__ int ech[LL];
    __shared__ unsigned short axFA[8*64*8];    // A-frags of x, 8 KB
    __shared__ unsigned short axFB[8*64*8];    // double buffer, 8 KB
    __shared__ unsigned short hxF[8*64*8];     // A-frags of h, 8 KB
    __shared__ int wcnt[2];                    // per-level wave-arrive counters
    __shared__ unsigned char rdyb[2][32];      // readiness bytes, (m,side) pairs

    int tid = threadIdx.x;
    int wg  = blockIdx.x;

    // ---- prologue: resolve all levels' descriptors + producer flags ----
    for (int i = tid; i < LL*NBK; i += 256) {
        int l = i >> 4, s = i & 15;
        unsigned short o = order[l*PAD16 + wg*NBK + s];
        int4 d; int2 d2 = make_int2(-1, -1);
        if (o == 0xFFFFu) {
            d = make_int4(-1, 0, 0, -1);
        } else {
            int gi = l*MM + (int)o;
            int t = types[gi];
            int e = (t >= TT) ? TT : t;
            int p0 = par[2*gi];
            int p1 = (t >= TT) ? ~(t - TT) : par[2*gi + 1];
            d = make_int4((int)o, p0, p1, e);
            if (p0 >= RR) d2.x = ((p0 - RR) >> 11)*CH + (int)chunkof[p0 - RR];
            if (p1 >= RR) d2.y = ((p1 - RR) >> 11)*CH + (int)chunkof[p1 - RR];
        }
        descs[l][s] = d;
        descs2[l][s] = d2;
    }
    if (tid == 0) { wcnt[0] = 0; wcnt[1] = 0; }
    __syncthreads();
    for (int i = tid; i < LL; i += 256) ech[i] = descs[i][0].w;
    __syncthreads();

    int w  = tid >> 6;    // wave 0..3
    int lq = tid & 63;    // lane
    int m_own  = tid >> 4;   // row this thread gathers
    int seg_own = tid & 15;  // 16-float segment

    // resolve this thread's gather source for level l1 (no flag loads here)
    #define RESOLVE(l1, S, PR, P) {                                            \
        int4 d_ = descs[l1][m_own];                                            \
        if (d_.x < 0) { P = true; S = nullptr; PR = -1; }                      \
        else {                                                                 \
            P = false;                                                         \
            int2 d2_ = descs2[l1][m_own];                                      \
            if (seg_own < 8)  { S = buf + (size_t)d_.y*DD + seg_own*16;        \
                                PR = (d2_.x >= 0) ? m_own*2 : -1; }            \
            else if (d_.z < 0){ S = slots + (size_t)(~d_.z)*DD + (seg_own-8)*16; PR = -1; } \
            else              { S = buf + (size_t)d_.z*DD + (seg_own-8)*16;    \
                                PR = (d2_.y >= 0) ? m_own*2 + 1 : -1; }        \
        } }

    #define WRITE_FRAGS(AXT, V0, V1, V2, V3) {                                 \
        unsigned short tA_[8], tB_[8];                                         \
        _Pragma("unroll")                                                      \
        for (int j = 0; j < 4; j++) {                                          \
            tA_[j]   = f2bf(V0[j]); tA_[4+j] = f2bf(V1[j]);                    \
            tB_[j]   = f2bf(V2[j]); tB_[4+j] = f2bf(V3[j]);                    \
        }                                                                      \
        int k_ = seg_own*16;                                                   \
        int kk_ = k_ >> 5, ln_ = m_own + 16*((k_ >> 3) & 3);                   \
        *(short8v*)&AXT[(kk_*64 + ln_)*8] = *(short8v*)tA_;                    \
        k_ += 8; kk_ = k_ >> 5; ln_ = m_own + 16*((k_ >> 3) & 3);              \
        *(short8v*)&AXT[(kk_*64 + ln_)*8] = *(short8v*)tB_;                    \
    }

    // checker helper: flag index for pair `tid` at level l1
    #define CHK_FI(l1) ((tid & 1) ? descs2[l1][tid >> 1].y : descs2[l1][tid >> 1].x)

    // ---- level-0 gather (roots/slots: always ready) ----
    {
        const float* src; int pr; bool pad;
        RESOLVE(0, src, pr, pad);
        f32x4 z = (f32x4){0.f,0.f,0.f,0.f};
        f32x4 v0 = z, v1 = z, v2 = z, v3 = z;
        if (!pad) {
            const f32x4* s4 = (const f32x4*)src;
            v0 = s4[0]; v1 = s4[1]; v2 = s4[2]; v3 = s4[3];
        }
        WRITE_FRAGS(axFA, v0, v1, v2, v3);
    }
    // ---- prologue: readiness snapshot for level 1 (checkers only) ----
    if (tid < 32) {
        int fi_ = CHK_FI(1);
        unsigned char r = 1;
        if (fi_ >= 0)
            r = (__hip_atomic_load(&flags[fi_], __ATOMIC_RELAXED,
                                   __HIP_MEMORY_SCOPE_AGENT) != 0u) ? 1 : 0;
        rdyb[1][tid] = r;
    }
    // per-thread gather carry for level 1
    const float* srcC = nullptr; int pairC = -1; bool padC = true;
    if (LL > 1) RESOLVE(1, srcC, pairC, padC);
    __syncthreads();

    unsigned short* axc = axFA;
    unsigned short* axn = axFB;

    for (int l = 0; l < LL; l++) {
        bool havN = (l + 1 < LL);
        int cur = (l + 1) & 1;     // readiness buffer for level l+1
        int nxt = l & 1;           // readiness buffer for level l+2
        if (tid == 0) wcnt[(l + 1) & 1] = 0;   // reset other-parity arrive counter

        // ---- phase A: row loads for LDS-confirmed-ready parents ----
        bool pend = false;
        f32x4 z = (f32x4){0.f,0.f,0.f,0.f};
        f32x4 v0 = z, v1 = z, v2 = z, v3 = z;
        if (havN && !padC) {
            bool ready = (pairC < 0) || (rdyb[cur][pairC] != 0);
            if (ready) {
                asm volatile("" ::: "memory");
                const f32x4* s4 = (const f32x4*)srcC;
                v0 = s4[0]; v1 = s4[1]; v2 = s4[2]; v3 = s4[3];
            } else {
                pend = true;
            }
        }
        // checkers: issue ONE fresh flag load per still-pending pair
        unsigned fv2 = 0; int fiChk = -1;
        if (havN && tid < 32) {
            int fi_ = CHK_FI(l + 1);
            if (fi_ >= 0 && rdyb[cur][tid] == 0) {
                fiChk = fi_;
                fv2 = __hip_atomic_load(&flags[fi_], __ATOMIC_RELAXED,
                                        __HIP_MEMORY_SCOPE_AGENT);
            }
        }
        __builtin_amdgcn_sched_barrier(0);   // pin: loads issued before compute

        int e = ech[l];
        if (e >= 0) {
            // ---- layer 1: H = GELU(X @ W1[e] + b1[e]) ----
            f32x4 acc[4];
            #pragma unroll
            for (int c = 0; c < 4; c++) {
                float bv = b1[e*256 + w*64 + c*16 + (lq & 15)];
                acc[c] = (f32x4){bv, bv, bv, bv};
            }
            {
                const short8v* Ab = (const short8v*)axc;
                #pragma unroll
                for (int kk = 0; kk < 8; kk++) {
                    short8v a = Ab[kk*64 + lq];
                    #pragma unroll
                    for (int c = 0; c < 4; c++) {
                        int nt = w*4 + c;
                        short8v bfr = *(const short8v*)&W1F[(((e*16 + nt)*8 + kk)*64 + lq)*8];
                        acc[c] = __builtin_amdgcn_mfma_f32_16x16x32_bf16(a, bfr, acc[c], 0, 0, 0);
                    }
                }
            }
            // ---- mid-check: consume checker re-loads, issue late row loads ----
            if (fiChk >= 0 && fv2 != 0u) rdyb[cur][tid] = 1;
            if (pend && *(volatile unsigned char*)&rdyb[cur][pairC]) {
                asm volatile("" ::: "memory");
                const f32x4* s4 = (const f32x4*)srcC;
                v0 = s4[0]; v1 = s4[1]; v2 = s4[2]; v3 = s4[3];
                pend = false;
            }
            __builtin_amdgcn_sched_barrier(0);

            #pragma unroll
            for (int c = 0; c < 4; c++) {
                int nh = w*64 + c*16 + (lq & 15);
                int kk2 = nh >> 5;
                int jj  = nh & 7;
                int lhi = 16*((nh >> 3) & 3);
                #pragma unroll
                for (int r = 0; r < 4; r++) {
                    int m = (lq >> 4)*4 + r;
                    hxF[(kk2*64 + (m + lhi))*8 + jj] = f2bf(gelu_f(acc[c][r]));
                }
            }
            __syncthreads();

            // ---- layer 2: OUT = H @ W2[e] + b2[e] ----
            f32x4 acc2[2];
            #pragma unroll
            for (int c = 0; c < 2; c++) {
                float bv = b2[e*128 + w*32 + c*16 + (lq & 15)];
                acc2[c] = (f32x4){bv, bv, bv, bv};
            }
            {
                const short8v* Hb = (const short8v*)hxF;
                #pragma unroll
                for (int kk = 0; kk < 8; kk++) {
                    short8v a = Hb[kk*64 + lq];
                    #pragma unroll
                    for (int c = 0; c < 2; c++) {
                        int nt = w*2 + c;
                        short8v bfr = *(const short8v*)&W2F[(((e*8 + nt)*8 + kk)*64 + lq)*8];
                        acc2[c] = __builtin_amdgcn_mfma_f32_16x16x32_bf16(a, bfr, acc2[c], 0, 0, 0);
                    }
                }
            }
            // result rows: sc1 write-through to the coherence point
            int baserow = RR + l*MM;
            #pragma unroll
            for (int r = 0; r < 4; r++) {
                int m = (lq >> 4)*4 + r;
                int node = descs[l][m].x;
                if (node >= 0) {
                    #pragma unroll
                    for (int c = 0; c < 2; c++) {
                        int n = w*32 + c*16 + (lq & 15);
                        __hip_atomic_store(&buf[(size_t)(baserow + node)*DD + n], acc2[c][r],
                                           __ATOMIC_RELAXED, __HIP_MEMORY_SCOPE_AGENT);
                    }
                }
            }
            // per-wave drain, LDS arrive, 4th wave publishes (no barrier)
            asm volatile("s_waitcnt vmcnt(0)" ::: "memory");
            if ((tid & 63) == 0) {
                int old = atomicAdd(&wcnt[l & 1], 1);
                if (old == 3)
                    __hip_atomic_store(&flags[l*CH + wg], 1u, __ATOMIC_RELAXED,
                                       __HIP_MEMORY_SCOPE_AGENT);
            }
        }

        // ---- snapshot issue for level l+2 (checkers; consumed at bottom) ----
        unsigned fvN = 1u; int fiNN = -1;
        if (l + 2 < LL && tid < 32) {
            fiNN = CHK_FI(l + 2);
            if (fiNN >= 0)
                fvN = __hip_atomic_load(&flags[fiNN], __ATOMIC_RELAXED,
                                        __HIP_MEMORY_SCOPE_AGENT);
        }

        // ---- phase B: checker spins on genuine stragglers; data spins on LDS ----
        if (havN) {
            if (tid < 32) {
                int fi_ = CHK_FI(l + 1);
                if (fi_ >= 0 && rdyb[cur][tid] == 0) {
                    while (__hip_atomic_load(&flags[fi_], __ATOMIC_RELAXED,
                                             __HIP_MEMORY_SCOPE_AGENT) == 0u)
                        __builtin_amdgcn_s_sleep(1);
                    rdyb[cur][tid] = 1;
                }
            }
            if (pend) {
                while (*(volatile unsigned char*)&rdyb[cur][pairC] == 0)
                    __builtin_amdgcn_s_sleep(1);
                asm volatile("" ::: "memory");
                const f32x4* s4 = (const f32x4*)srcC;
                v0 = s4[0]; v1 = s4[1]; v2 = s4[2]; v3 = s4[3];
            }
            WRITE_FRAGS(axn, v0, v1, v2, v3);
        }

        // ---- write snapshot, resolve per-thread carry for l+2 ----
        if (l + 2 < LL && tid < 32)
            rdyb[nxt][tid] = (fiNN < 0) ? 1 : ((fvN != 0u) ? 1 : 0);
        const float* srcN = nullptr; int pairN = -1; bool padN = true;
        if (l + 2 < LL) RESOLVE(l+2, srcN, pairN, padN);
        __syncthreads();
        unsigned short* t2 = axc; axc = axn; axn = t2;
        srcC = srcN; pairC = pairN; padC = padN;
    }
}

extern "C" void kernel_launch(void* const* d_in, const int* in_sizes, int n_in,
                              void* d_out, int out_size, void* d_ws, size_t ws_size,
                              hipStream_t stream) {
    const float* root  = (const float*)d_in[0];   // (1024, 128)
    const float* W1    = (const float*)d_in[1];   // (5, 256, 256)
    const float* b1    = (const float*)d_in[2];   // (5, 256)
    const float* W2    = (const float*)d_in[3];   // (5, 256, 128)
    const float* b2    = (const float*)d_in[4];   // (5, 128)
    const float* slots = (const float*)d_in[5];   // (256, 128)
    const int*   par   = (const int*)d_in[6];     // (131072, 2)
    const int*   typ   = (const int*)d_in[7];     // (131072,)
    float* out = (float*)d_out;                   // (132096, 128)

    unsigned short* W1F     = (unsigned short*)d_ws;          // 327680 shorts
    unsigned short* W2F     = W1F + 5*16*8*64*8;              // 163840 shorts
    unsigned short* order   = W2F + 5*8*8*64*8;               // 64*2208 shorts
    unsigned char*  chunkof = (unsigned char*)(order + LL*PAD16);  // 131072 B
    unsigned int*   flags   = (unsigned int*)(chunkof + LL*MM);    // 64*138 u32

    // single fused prep dispatch (order/chunkof, weights, roots, flags)
    prep_all<<<LL + 240 + 32 + 1, 256, 0, stream>>>(root, W1, W2, typ, par, out,
                                                    W1F, W2F, order, chunkof, flags);

    // persistent dataflow sweep (co-residency guaranteed by cooperative launch)
    void* args[] = { (void*)&W1F, (void*)&W2F, (void*)&b1, (void*)&b2,
                     (void*)&slots, (void*)&par, (void*)&typ, (void*)&order,
                     (void*)&chunkof, (void*)&out, (void*)&flags };
    hipLaunchCooperativeKernel((const void*)persist_mfma, dim3(CH), dim3(256),
                               args, 0, stream);
}

// Round 12
// 266.414 us; speedup vs baseline: 1.6537x; 1.4723x over previous
//
#include <hip/hip_runtime.h>
#include <math.h>

#define DD 128          // node embedding dim
#define RR 1024         // root nodes
#define TT 4            // trunk types; encoder TT is the output autoencoder
#define LL 64           // levels
#define MM 2048         // nodes per level
#define NBK 16          // nodes per chunk (one MFMA M-tile)
#define GT 37           // chunk slots per trunk type (cap 592 nodes, mean 486, 5.4σ)
#define GO 10           // chunk slots for output type (cap 160, mean 102, 5.8σ)
#define CCAP (4*GT + GO)       // 158 global chunk slots per level == #WGs
#define PAD16 (CCAP*NBK)       // 2528 order slots per level
#define CH CCAP

typedef __attribute__((ext_vector_type(8))) short short8v;   // 8 bf16 (4 VGPRs)
typedef __attribute__((ext_vector_type(4))) float f32x4;

static __device__ __forceinline__ unsigned short f2bf(float f) {
    unsigned u = __float_as_uint(f);
    unsigned r = (u + 0x7fffu + ((u >> 16) & 1u)) >> 16;   // RNE
    return (unsigned short)r;
}

// A&S 7.1.26 erf (|err| < 1.5e-7), branchless
static __device__ __forceinline__ float gelu_f(float h) {
    float x  = h * 0.70710678118654752f;
    float ax = fabsf(x);
    float t  = __builtin_amdgcn_rcpf(fmaf(0.3275911f, ax, 1.0f));
    float p  = fmaf(t, 1.061405429f, -1.453152027f);
    p = fmaf(p, t, 1.421413741f);
    p = fmaf(p, t, -0.284496736f);
    p = fmaf(p, t, 0.254829592f);
    p = p * t;
    float er = 1.0f - p * __expf(-ax * ax);
    er = copysignf(er, x);
    return 0.5f * h * (1.0f + er);
}

// ---------------------------------------------------------------------------
// Fused prep. Bucketing: fixed per-type chunk regions (type e trunk at chunk
// base e*GT, out at 4*GT), sail (no level-(l-1) parent) packed before gate
// within each region. chunkof[node] = GLOBAL chunk id. One WG per chunk slot.
// ---------------------------------------------------------------------------
__global__ __launch_bounds__(256) void prep_all(
    const float* __restrict__ root, const float* __restrict__ W1,
    const float* __restrict__ W2, const int* __restrict__ types,
    const int* __restrict__ par,
    float* __restrict__ buf,
    unsigned short* __restrict__ W1F, unsigned short* __restrict__ W2F,
    unsigned short* __restrict__ order, unsigned char* __restrict__ chunkof,
    unsigned int* __restrict__ flags)
{
    int bid = blockIdx.x, tid = threadIdx.x;
    if (bid < LL) {
        int l = bid;
        __shared__ int cnt[10], cur[10];
        if (tid < 10) cnt[tid] = 0;
        __syncthreads();
        for (int s = tid; s < PAD16; s += 256) order[l*PAD16 + s] = 0xFFFFu;
        int thr = RR + (l-1)*MM;    // parents >= thr come from level l-1
        for (int m = tid; m < MM; m += 256) {
            int gi = l*MM + m;
            int t = types[gi];
            int e = (t >= TT) ? TT : t;
            int p0 = par[2*gi];
            bool rec = (p0 >= RR) && (p0 >= thr);
            if (t < TT) {
                int p1 = par[2*gi + 1];
                rec = rec || ((p1 >= RR) && (p1 >= thr));
            }
            atomicAdd(&cnt[e*2 + (rec ? 1 : 0)], 1);
        }
        __syncthreads();
        if (tid == 0) {
            for (int e = 0; e < 5; e++) {
                int base = ((e < 4) ? e*GT : 4*GT) * NBK;
                int s = cnt[e*2];
                cur[e*2]     = base;
                cur[e*2 + 1] = base + ((s + NBK - 1)/NBK)*NBK;
            }
        }
        __syncthreads();
        for (int m = tid; m < MM; m += 256) {
            int gi = l*MM + m;
            int t = types[gi];
            int e = (t >= TT) ? TT : t;
            int p0 = par[2*gi];
            bool rec = (p0 >= RR) && (p0 >= thr);
            if (t < TT) {
                int p1 = par[2*gi + 1];
                rec = rec || ((p1 >= RR) && (p1 >= thr));
            }
            int pos = atomicAdd(&cur[e*2 + (rec ? 1 : 0)], 1);
            order[l*PAD16 + pos] = (unsigned short)m;
            chunkof[l*MM + m] = (unsigned char)(pos >> 4);   // global chunk id
        }
    } else if (bid < LL + 240) {
        int t0 = (bid - LL)*256 + tid;
        if (t0 < 5*16*8*64) {
            int lane = t0 & 63;
            int kk = (t0 >> 6) & 7;
            int nt = (t0 >> 9) & 15;
            int e  = t0 >> 13;
            int n  = nt*16 + (lane & 15);
            int k0 = kk*32 + (lane >> 4)*8;
            unsigned short v[8];
            #pragma unroll
            for (int j = 0; j < 8; j++) v[j] = f2bf(W1[(e*256 + k0 + j)*256 + n]);
            *(short8v*)&W1F[t0*8] = *(short8v*)v;
        } else {
            int t = t0 - 5*16*8*64;   // < 20480
            int lane = t & 63;
            int kk = (t >> 6) & 7;
            int nt = (t >> 9) & 7;
            int e  = t >> 12;
            int n  = nt*16 + (lane & 15);
            int k0 = kk*32 + (lane >> 4)*8;
            unsigned short v[8];
            #pragma unroll
            for (int j = 0; j < 8; j++) v[j] = f2bf(W2[(e*256 + k0 + j)*128 + n]);
            *(short8v*)&W2F[t*8] = *(short8v*)v;
        }
    } else if (bid < LL + 240 + 32) {
        int idx = (bid - (LL + 240))*256 + tid;   // 0..8191
        const f32x4* r4 = (const f32x4*)root;
        f32x4* o4 = (f32x4*)buf;
        #pragma unroll
        for (int q = 0; q < 4; q++) o4[idx*4 + q] = r4[idx*4 + q];
    } else {
        for (int i = tid; i < LL*CCAP; i += 256) flags[i] = 0u;
    }
}

// ---------------------------------------------------------------------------
// Persistent dataflow kernel: CCAP WGs x 512 threads (8 waves, 2/SIMD).
// WG wg has a STATIC encoder type -> its weight B-fragments live in VGPRs for
// the whole kernel (wave w: W1 nt=2w,2w+1; W2 nt=w; 96 VGPR). Per level:
// 8 ds_reads + 16 MFMA (L1), GELU, 8 ds_reads + 8 MFMA (L2) -- zero weight
// memory traffic. Flag traffic via 32 checker lanes -> LDS readiness bytes.
// Producer protocol (validated r7-r11): sc1 stores -> per-thread vmcnt(0) ->
// 8-wave LDS arrive -> sc1 flag publish. Sail/gate bucketing from r11.
// ---------------------------------------------------------------------------
__global__ __launch_bounds__(512, 2) void persist_mfma(
    const unsigned short* __restrict__ W1F, const unsigned short* __restrict__ W2F,
    const float* __restrict__ b1, const float* __restrict__ b2,
    const float* __restrict__ slots, const int* __restrict__ par,
    const int* __restrict__ types, const unsigned short* __restrict__ order,
    const unsigned char* __restrict__ chunkof,
    float* __restrict__ buf, unsigned int* __restrict__ flags)
{
    __shared__ int4 descs[LL][NBK];            // {node, p0, p1(~slot if out), etype}
    __shared__ int2 descs2[LL][NBK];           // producer flag idx per parent (-1 ready)
    __shared__ int ech[LL];
    __shared__ unsigned short axFA[8*64*8];    // A-frags of x, 8 KB
    __shared__ unsigned short axFB[8*64*8];    // double buffer, 8 KB
    __shared__ unsigned short hxF[8*64*8];     // A-frags of h, 8 KB
    __shared__ int wcnt[2];                    // per-level wave-arrive counters
    __shared__ unsigned char rdyb[2][32];      // readiness bytes, (m,side) pairs

    int tid = threadIdx.x;
    int wg  = blockIdx.x;
    int e_wg = (wg < 4*GT) ? (wg / GT) : TT;   // static encoder type of this WG

    int w  = tid >> 6;    // wave 0..7
    int lq = tid & 63;    // lane
    int m_own   = tid >> 4;   // gather row (tid<256)
    int seg_own = tid & 15;   // 16-float segment

    // ---- preload weight B-fragments + biases into registers ----
    short8v w1r0[8], w1r1[8], w2r[8];
    #pragma unroll
    for (int kk = 0; kk < 8; kk++) {
        w1r0[kk] = *(const short8v*)&W1F[(((e_wg*16 + 2*w + 0)*8 + kk)*64 + lq)*8];
        w1r1[kk] = *(const short8v*)&W1F[(((e_wg*16 + 2*w + 1)*8 + kk)*64 + lq)*8];
        w2r[kk]  = *(const short8v*)&W2F[(((e_wg*8  + w)*8 + kk)*64 + lq)*8];
    }
    float b1v0 = b1[e_wg*256 + (2*w + 0)*16 + (lq & 15)];
    float b1v1 = b1[e_wg*256 + (2*w + 1)*16 + (lq & 15)];
    float b2v  = b2[e_wg*128 + w*16 + (lq & 15)];

    // ---- prologue: resolve all levels' descriptors + producer flags ----
    for (int i = tid; i < LL*NBK; i += 512) {
        int l = i >> 4, s = i & 15;
        unsigned short o = order[l*PAD16 + wg*NBK + s];
        int4 d; int2 d2 = make_int2(-1, -1);
        if (o == 0xFFFFu) {
            d = make_int4(-1, 0, 0, -1);
        } else {
            int gi = l*MM + (int)o;
            int t = types[gi];
            int e = (t >= TT) ? TT : t;
            int p0 = par[2*gi];
            int p1 = (t >= TT) ? ~(t - TT) : par[2*gi + 1];
            d = make_int4((int)o, p0, p1, e);
            if (p0 >= RR) d2.x = ((p0 - RR) >> 11)*CCAP + (int)chunkof[p0 - RR];
            if (p1 >= RR) d2.y = ((p1 - RR) >> 11)*CCAP + (int)chunkof[p1 - RR];
        }
        descs[l][s] = d;
        descs2[l][s] = d2;
    }
    if (tid == 0) { wcnt[0] = 0; wcnt[1] = 0; }
    __syncthreads();
    for (int i = tid; i < LL; i += 512) ech[i] = descs[i][0].w;
    __syncthreads();

    #define RESOLVE(l1, S, PR, P) {                                            \
        int4 d_ = descs[l1][m_own];                                            \
        if (d_.x < 0) { P = true; S = nullptr; PR = -1; }                      \
        else {                                                                 \
            P = false;                                                         \
            int2 d2_ = descs2[l1][m_own];                                      \
            if (seg_own < 8)  { S = buf + (size_t)d_.y*DD + seg_own*16;        \
                                PR = (d2_.x >= 0) ? m_own*2 : -1; }            \
            else if (d_.z < 0){ S = slots + (size_t)(~d_.z)*DD + (seg_own-8)*16; PR = -1; } \
            else              { S = buf + (size_t)d_.z*DD + (seg_own-8)*16;    \
                                PR = (d2_.y >= 0) ? m_own*2 + 1 : -1; }        \
        } }

    #define WRITE_FRAGS(AXT, V0, V1, V2, V3) {                                 \
        unsigned short tA_[8], tB_[8];                                         \
        _Pragma("unroll")                                                      \
        for (int j = 0; j < 4; j++) {                                          \
            tA_[j]   = f2bf(V0[j]); tA_[4+j] = f2bf(V1[j]);                    \
            tB_[j]   = f2bf(V2[j]); tB_[4+j] = f2bf(V3[j]);                    \
        }                                                                      \
        int k_ = seg_own*16;                                                   \
        int kk_ = k_ >> 5, ln_ = m_own + 16*((k_ >> 3) & 3);                   \
        *(short8v*)&AXT[(kk_*64 + ln_)*8] = *(short8v*)tA_;                    \
        k_ += 8; kk_ = k_ >> 5; ln_ = m_own + 16*((k_ >> 3) & 3);              \
        *(short8v*)&AXT[(kk_*64 + ln_)*8] = *(short8v*)tB_;                    \
    }

    // checker helper: flag index for pair `tid` at level l1 (tid < 32)
    #define CHK_FI(l1) ((tid & 1) ? descs2[l1][tid >> 1].y : descs2[l1][tid >> 1].x)

    // ---- level-0 gather (roots/slots: always ready) ----
    if (tid < 256) {
        const float* src; int pr; bool pad;
        RESOLVE(0, src, pr, pad);
        f32x4 z = (f32x4){0.f,0.f,0.f,0.f};
        f32x4 v0 = z, v1 = z, v2 = z, v3 = z;
        if (!pad) {
            const f32x4* s4 = (const f32x4*)src;
            v0 = s4[0]; v1 = s4[1]; v2 = s4[2]; v3 = s4[3];
        }
        WRITE_FRAGS(axFA, v0, v1, v2, v3);
    }
    // ---- prologue: readiness snapshot for level 1 (checkers only) ----
    if (tid < 32) {
        int fi_ = CHK_FI(1);
        unsigned char r = 1;
        if (fi_ >= 0)
            r = (__hip_atomic_load(&flags[fi_], __ATOMIC_RELAXED,
                                   __HIP_MEMORY_SCOPE_AGENT) != 0u) ? 1 : 0;
        rdyb[1][tid] = r;
    }
    // per-thread gather carry for level 1
    const float* srcC = nullptr; int pairC = -1; bool padC = true;
    if (tid < 256) { RESOLVE(1, srcC, pairC, padC); }
    __syncthreads();

    unsigned short* axc = axFA;
    unsigned short* axn = axFB;

    for (int l = 0; l < LL; l++) {
        bool havN = (l + 1 < LL);
        int cur = (l + 1) & 1;     // readiness buffer for level l+1
        int nxt = l & 1;           // readiness buffer for level l+2
        if (tid == 0) wcnt[(l + 1) & 1] = 0;

        // ---- phase A: row loads for LDS-confirmed-ready parents (tid<256) ----
        bool pend = false;
        f32x4 z = (f32x4){0.f,0.f,0.f,0.f};
        f32x4 v0 = z, v1 = z, v2 = z, v3 = z;
        if (havN && tid < 256 && !padC) {
            bool ready = (pairC < 0) || (rdyb[cur][pairC] != 0);
            if (ready) {
                asm volatile("" ::: "memory");
                const f32x4* s4 = (const f32x4*)srcC;
                v0 = s4[0]; v1 = s4[1]; v2 = s4[2]; v3 = s4[3];
            } else {
                pend = true;
            }
        }
        // checkers: one fresh flag load per still-pending pair
        unsigned fv2 = 0; int fiChk = -1;
        if (havN && tid < 32) {
            int fi_ = CHK_FI(l + 1);
            if (fi_ >= 0 && rdyb[cur][tid] == 0) {
                fiChk = fi_;
                fv2 = __hip_atomic_load(&flags[fi_], __ATOMIC_RELAXED,
                                        __HIP_MEMORY_SCOPE_AGENT);
            }
        }
        __builtin_amdgcn_sched_barrier(0);   // pin: loads issued before compute

        int e = ech[l];
        if (e >= 0) {
            // ---- layer 1: H = GELU(X @ W1 + b1), weights in VGPRs ----
            f32x4 acc0 = (f32x4){b1v0, b1v0, b1v0, b1v0};
            f32x4 acc1 = (f32x4){b1v1, b1v1, b1v1, b1v1};
            {
                const short8v* Ab = (const short8v*)axc;
                #pragma unroll
                for (int kk = 0; kk < 8; kk++) {
                    short8v a = Ab[kk*64 + lq];
                    acc0 = __builtin_amdgcn_mfma_f32_16x16x32_bf16(a, w1r0[kk], acc0, 0, 0, 0);
                    acc1 = __builtin_amdgcn_mfma_f32_16x16x32_bf16(a, w1r1[kk], acc1, 0, 0, 0);
                }
            }
            // ---- mid-check: consume checker re-loads, issue late row loads ----
            if (fiChk >= 0 && fv2 != 0u) rdyb[cur][tid] = 1;
            if (pend && *(volatile unsigned char*)&rdyb[cur][pairC]) {
                asm volatile("" ::: "memory");
                const f32x4* s4 = (const f32x4*)srcC;
                v0 = s4[0]; v1 = s4[1]; v2 = s4[2]; v3 = s4[3];
                pend = false;
            }
            __builtin_amdgcn_sched_barrier(0);

            // GELU + scatter H into A-frag LDS (nt = 2w+c, c in {0,1})
            #pragma unroll
            for (int c = 0; c < 2; c++) {
                int nh = (2*w + c)*16 + (lq & 15);
                int kk2 = nh >> 5;
                int jj  = nh & 7;
                int lhi = 16*((nh >> 3) & 3);
                #pragma unroll
                for (int r = 0; r < 4; r++) {
                    int m = (lq >> 4)*4 + r;
                    float h = (c == 0) ? acc0[r] : acc1[r];
                    hxF[(kk2*64 + (m + lhi))*8 + jj] = f2bf(gelu_f(h));
                }
            }
            __syncthreads();

            // ---- layer 2: OUT = H @ W2 + b2 (nt = w) ----
            f32x4 acc2 = (f32x4){b2v, b2v, b2v, b2v};
            {
                const short8v* Hb = (const short8v*)hxF;
                #pragma unroll
                for (int kk = 0; kk < 8; kk++) {
                    short8v a = Hb[kk*64 + lq];
                    acc2 = __builtin_amdgcn_mfma_f32_16x16x32_bf16(a, w2r[kk], acc2, 0, 0, 0);
                }
            }
            // result rows: sc1 write-through to the coherence point
            int baserow = RR + l*MM;
            int n = w*16 + (lq & 15);
            #pragma unroll
            for (int r = 0; r < 4; r++) {
                int m = (lq >> 4)*4 + r;
                int node = descs[l][m].x;
                if (node >= 0)
                    __hip_atomic_store(&buf[(size_t)(baserow + node)*DD + n], acc2[r],
                                       __ATOMIC_RELAXED, __HIP_MEMORY_SCOPE_AGENT);
            }
            // per-thread drain: sc1 store retire => at coherence point
            asm volatile("s_waitcnt vmcnt(0)" ::: "memory");
            if ((tid & 63) == 0) {
                int old = atomicAdd(&wcnt[l & 1], 1);
                if (old == 7)
                    __hip_atomic_store(&flags[l*CCAP + wg], 1u, __ATOMIC_RELAXED,
                                       __HIP_MEMORY_SCOPE_AGENT);
            }
        }

        // ---- snapshot issue for level l+2 (checkers; consumed at bottom) ----
        unsigned fvN = 1u; int fiNN = -1;
        if (l + 2 < LL && tid < 32) {
            fiNN = CHK_FI(l + 2);
            if (fiNN >= 0)
                fvN = __hip_atomic_load(&flags[fiNN], __ATOMIC_RELAXED,
                                        __HIP_MEMORY_SCOPE_AGENT);
        }

        // ---- phase B: checker spins on stragglers; data spins on LDS ----
        if (havN) {
            if (tid < 32) {
                int fi_ = CHK_FI(l + 1);
                if (fi_ >= 0 && rdyb[cur][tid] == 0) {
                    while (__hip_atomic_load(&flags[fi_], __ATOMIC_RELAXED,
                                             __HIP_MEMORY_SCOPE_AGENT) == 0u)
                        __builtin_amdgcn_s_sleep(1);
                    rdyb[cur][tid] = 1;
                }
            }
            if (tid < 256) {
                if (pend) {
                    while (*(volatile unsigned char*)&rdyb[cur][pairC] == 0)
                        __builtin_amdgcn_s_sleep(1);
                    asm volatile("" ::: "memory");
                    const f32x4* s4 = (const f32x4*)srcC;
                    v0 = s4[0]; v1 = s4[1]; v2 = s4[2]; v3 = s4[3];
                }
                WRITE_FRAGS(axn, v0, v1, v2, v3);
            }
        }

        // ---- write snapshot, resolve per-thread carry for l+2 ----
        if (l + 2 < LL && tid < 32)
            rdyb[nxt][tid] = (fiNN < 0) ? 1 : ((fvN != 0u) ? 1 : 0);
        const float* srcN = nullptr; int pairN = -1; bool padN = true;
        if (l + 2 < LL && tid < 256) { RESOLVE(l+2, srcN, pairN, padN); }
        __syncthreads();
        unsigned short* t2 = axc; axc = axn; axn = t2;
        srcC = srcN; pairC = pairN; padC = padN;
    }
}

extern "C" void kernel_launch(void* const* d_in, const int* in_sizes, int n_in,
                              void* d_out, int out_size, void* d_ws, size_t ws_size,
                              hipStream_t stream) {
    const float* root  = (const float*)d_in[0];   // (1024, 128)
    const float* W1    = (const float*)d_in[1];   // (5, 256, 256)
    const float* b1    = (const float*)d_in[2];   // (5, 256)
    const float* W2    = (const float*)d_in[3];   // (5, 256, 128)
    const float* b2    = (const float*)d_in[4];   // (5, 128)
    const float* slots = (const float*)d_in[5];   // (256, 128)
    const int*   par   = (const int*)d_in[6];     // (131072, 2)
    const int*   typ   = (const int*)d_in[7];     // (131072,)
    float* out = (float*)d_out;                   // (132096, 128)

    unsigned short* W1F     = (unsigned short*)d_ws;          // 327680 shorts
    unsigned short* W2F     = W1F + 5*16*8*64*8;              // 163840 shorts
    unsigned short* order   = W2F + 5*8*8*64*8;               // 64*2528 shorts
    unsigned char*  chunkof = (unsigned char*)(order + LL*PAD16);  // 131072 B
    unsigned int*   flags   = (unsigned int*)(chunkof + LL*MM);    // 64*158 u32

    // single fused prep dispatch (order/chunkof, weights, roots, flags)
    prep_all<<<LL + 240 + 32 + 1, 256, 0, stream>>>(root, W1, W2, typ, par, out,
                                                    W1F, W2F, order, chunkof, flags);

    // persistent dataflow sweep (co-residency guaranteed by cooperative launch)
    void* args[] = { (void*)&W1F, (void*)&W2F, (void*)&b1, (void*)&b2,
                     (void*)&slots, (void*)&par, (void*)&typ, (void*)&order,
                     (void*)&chunkof, (void*)&out, (void*)&flags };
    hipLaunchCooperativeKernel((const void*)persist_mfma, dim3(CH), dim3(512),
                               args, 0, stream);
}

// Round 13
// 255.142 us; speedup vs baseline: 1.7267x; 1.0442x over previous
//
#include <hip/hip_runtime.h>
#include <math.h>

#define DD 128          // node embedding dim
#define RR 1024         // root nodes
#define TT 4            // trunk types; encoder TT is the output autoencoder
#define LL 64           // levels
#define MM 2048         // nodes per level
#define NBK 16          // nodes per chunk (one MFMA M-tile)
#define GT 37           // chunk slots per trunk type (cap 592 nodes, mean 486, 5.4σ)
#define GO 10           // chunk slots for output type (cap 160, mean 102, 5.8σ)
#define CCAP (4*GT + GO)       // 158 global chunk slots per level == #WGs
#define PAD16 (CCAP*NBK)       // 2528 order slots per level
#define CH CCAP

typedef __attribute__((ext_vector_type(8))) short short8v;   // 8 bf16 (4 VGPRs)
typedef __attribute__((ext_vector_type(4))) float f32x4;

static __device__ __forceinline__ unsigned short f2bf(float f) {
    unsigned u = __float_as_uint(f);
    unsigned r = (u + 0x7fffu + ((u >> 16) & 1u)) >> 16;   // RNE
    return (unsigned short)r;
}

// A&S 7.1.26 erf (|err| < 1.5e-7), branchless
static __device__ __forceinline__ float gelu_f(float h) {
    float x  = h * 0.70710678118654752f;
    float ax = fabsf(x);
    float t  = __builtin_amdgcn_rcpf(fmaf(0.3275911f, ax, 1.0f));
    float p  = fmaf(t, 1.061405429f, -1.453152027f);
    p = fmaf(p, t, 1.421413741f);
    p = fmaf(p, t, -0.284496736f);
    p = fmaf(p, t, 0.254829592f);
    p = p * t;
    float er = 1.0f - p * __expf(-ax * ax);
    er = copysignf(er, x);
    return 0.5f * h * (1.0f + er);
}

// ---------------------------------------------------------------------------
// Fused prep. Bucketing (r11/r12): fixed per-type chunk regions, sail packed
// before gate within each region. chunkof[node] = GLOBAL chunk id.
// Flags are per (level, chunk, wave): LL*CCAP*8 u32.
// ---------------------------------------------------------------------------
__global__ __launch_bounds__(256) void prep_all(
    const float* __restrict__ root, const float* __restrict__ W1,
    const float* __restrict__ W2, const int* __restrict__ types,
    const int* __restrict__ par,
    float* __restrict__ buf,
    unsigned short* __restrict__ W1F, unsigned short* __restrict__ W2F,
    unsigned short* __restrict__ order, unsigned char* __restrict__ chunkof,
    unsigned int* __restrict__ flags)
{
    int bid = blockIdx.x, tid = threadIdx.x;
    if (bid < LL) {
        int l = bid;
        __shared__ int cnt[10], cur[10];
        if (tid < 10) cnt[tid] = 0;
        __syncthreads();
        for (int s = tid; s < PAD16; s += 256) order[l*PAD16 + s] = 0xFFFFu;
        int thr = RR + (l-1)*MM;    // parents >= thr come from level l-1
        for (int m = tid; m < MM; m += 256) {
            int gi = l*MM + m;
            int t = types[gi];
            int e = (t >= TT) ? TT : t;
            int p0 = par[2*gi];
            bool rec = (p0 >= RR) && (p0 >= thr);
            if (t < TT) {
                int p1 = par[2*gi + 1];
                rec = rec || ((p1 >= RR) && (p1 >= thr));
            }
            atomicAdd(&cnt[e*2 + (rec ? 1 : 0)], 1);
        }
        __syncthreads();
        if (tid == 0) {
            for (int e = 0; e < 5; e++) {
                int base = ((e < 4) ? e*GT : 4*GT) * NBK;
                int s = cnt[e*2];
                cur[e*2]     = base;
                cur[e*2 + 1] = base + ((s + NBK - 1)/NBK)*NBK;
            }
        }
        __syncthreads();
        for (int m = tid; m < MM; m += 256) {
            int gi = l*MM + m;
            int t = types[gi];
            int e = (t >= TT) ? TT : t;
            int p0 = par[2*gi];
            bool rec = (p0 >= RR) && (p0 >= thr);
            if (t < TT) {
                int p1 = par[2*gi + 1];
                rec = rec || ((p1 >= RR) && (p1 >= thr));
            }
            int pos = atomicAdd(&cur[e*2 + (rec ? 1 : 0)], 1);
            order[l*PAD16 + pos] = (unsigned short)m;
            chunkof[l*MM + m] = (unsigned char)(pos >> 4);   // global chunk id
        }
    } else if (bid < LL + 240) {
        int t0 = (bid - LL)*256 + tid;
        if (t0 < 5*16*8*64) {
            int lane = t0 & 63;
            int kk = (t0 >> 6) & 7;
            int nt = (t0 >> 9) & 15;
            int e  = t0 >> 13;
            int n  = nt*16 + (lane & 15);
            int k0 = kk*32 + (lane >> 4)*8;
            unsigned short v[8];
            #pragma unroll
            for (int j = 0; j < 8; j++) v[j] = f2bf(W1[(e*256 + k0 + j)*256 + n]);
            *(short8v*)&W1F[t0*8] = *(short8v*)v;
        } else {
            int t = t0 - 5*16*8*64;   // < 20480
            int lane = t & 63;
            int kk = (t >> 6) & 7;
            int nt = (t >> 9) & 7;
            int e  = t >> 12;
            int n  = nt*16 + (lane & 15);
            int k0 = kk*32 + (lane >> 4)*8;
            unsigned short v[8];
            #pragma unroll
            for (int j = 0; j < 8; j++) v[j] = f2bf(W2[(e*256 + k0 + j)*128 + n]);
            *(short8v*)&W2F[t*8] = *(short8v*)v;
        }
    } else if (bid < LL + 240 + 32) {
        int idx = (bid - (LL + 240))*256 + tid;   // 0..8191
        const f32x4* r4 = (const f32x4*)root;
        f32x4* o4 = (f32x4*)buf;
        #pragma unroll
        for (int q = 0; q < 4; q++) o4[idx*4 + q] = r4[idx*4 + q];
    } else {
        // zero per-wave flags: LL*CCAP*8 u32
        int idx = (bid - (LL + 240 + 32))*256 + tid;
        if (idx < (LL*CCAP*8)/8) {
            #pragma unroll
            for (int q = 0; q < 8; q++) flags[idx*8 + q] = 0u;
        }
    }
}

// ---------------------------------------------------------------------------
// Persistent dataflow kernel: CCAP WGs x 512 threads (8 waves, 2/SIMD).
// Static encoder type per WG; weights live in VGPRs (r12). PER-WAVE flags:
// producer wave w writes columns [16w,16w+16) of all 16 node rows, drains its
// own sc1 stores (vmcnt is per-wave), then immediately publishes its own flag
// -- no cross-wave arrive. Consumer thread (m, seg) depends on exactly wave
// seg (or seg-8) of the parent's chunk -> per-thread flag index. Snapshot
// carried 1 level, fresh re-load hidden under L1 MFMA, phase-B spin only for
// genuine same-level (gate) parents. Sail/gate bucketing from r11.
// ---------------------------------------------------------------------------
__global__ __launch_bounds__(512, 2) void persist_mfma(
    const unsigned short* __restrict__ W1F, const unsigned short* __restrict__ W2F,
    const float* __restrict__ b1, const float* __restrict__ b2,
    const float* __restrict__ slots, const int* __restrict__ par,
    const int* __restrict__ types, const unsigned short* __restrict__ order,
    const unsigned char* __restrict__ chunkof,
    float* __restrict__ buf, unsigned int* __restrict__ flags)
{
    __shared__ int4 descs[LL][NBK];            // {node, p0, p1(~slot if out), etype}
    __shared__ int2 descs2[LL][NBK];           // producer chunk flag base per parent
    __shared__ int ech[LL];
    __shared__ unsigned short axFA[8*64*8];    // A-frags of x, 8 KB
    __shared__ unsigned short axFB[8*64*8];    // double buffer, 8 KB
    __shared__ unsigned short hxF[8*64*8];     // A-frags of h, 8 KB

    int tid = threadIdx.x;
    int wg  = blockIdx.x;
    int e_wg = (wg < 4*GT) ? (wg / GT) : TT;   // static encoder type of this WG

    int w  = tid >> 6;    // wave 0..7
    int lq = tid & 63;    // lane
    int m_own   = tid >> 4;   // gather row (tid<256)
    int seg_own = tid & 15;   // 16-float segment

    // ---- preload weight B-fragments + biases into registers ----
    short8v w1r0[8], w1r1[8], w2r[8];
    #pragma unroll
    for (int kk = 0; kk < 8; kk++) {
        w1r0[kk] = *(const short8v*)&W1F[(((e_wg*16 + 2*w + 0)*8 + kk)*64 + lq)*8];
        w1r1[kk] = *(const short8v*)&W1F[(((e_wg*16 + 2*w + 1)*8 + kk)*64 + lq)*8];
        w2r[kk]  = *(const short8v*)&W2F[(((e_wg*8  + w)*8 + kk)*64 + lq)*8];
    }
    float b1v0 = b1[e_wg*256 + (2*w + 0)*16 + (lq & 15)];
    float b1v1 = b1[e_wg*256 + (2*w + 1)*16 + (lq & 15)];
    float b2v  = b2[e_wg*128 + w*16 + (lq & 15)];

    // ---- prologue: resolve all levels' descriptors + producer chunk bases ----
    for (int i = tid; i < LL*NBK; i += 512) {
        int l = i >> 4, s = i & 15;
        unsigned short o = order[l*PAD16 + wg*NBK + s];
        int4 d; int2 d2 = make_int2(-1, -1);
        if (o == 0xFFFFu) {
            d = make_int4(-1, 0, 0, -1);
        } else {
            int gi = l*MM + (int)o;
            int t = types[gi];
            int e = (t >= TT) ? TT : t;
            int p0 = par[2*gi];
            int p1 = (t >= TT) ? ~(t - TT) : par[2*gi + 1];
            d = make_int4((int)o, p0, p1, e);
            if (p0 >= RR) d2.x = ((p0 - RR) >> 11)*CCAP + (int)chunkof[p0 - RR];
            if (p1 >= RR) d2.y = ((p1 - RR) >> 11)*CCAP + (int)chunkof[p1 - RR];
        }
        descs[l][s] = d;
        descs2[l][s] = d2;
    }
    __syncthreads();
    for (int i = tid; i < LL; i += 512) ech[i] = descs[i][0].w;
    __syncthreads();

    // resolve this thread's gather source + per-wave flag index for level l1
    #define RESOLVE(l1, S, F8, P) {                                            \
        int4 d_ = descs[l1][m_own];                                            \
        if (d_.x < 0) { P = true; S = nullptr; F8 = -1; }                      \
        else {                                                                 \
            P = false;                                                         \
            int2 d2_ = descs2[l1][m_own];                                      \
            if (seg_own < 8)  { S = buf + (size_t)d_.y*DD + seg_own*16;        \
                                F8 = (d2_.x >= 0) ? d2_.x*8 + seg_own : -1; }  \
            else if (d_.z < 0){ S = slots + (size_t)(~d_.z)*DD + (seg_own-8)*16; F8 = -1; } \
            else              { S = buf + (size_t)d_.z*DD + (seg_own-8)*16;    \
                                F8 = (d2_.y >= 0) ? d2_.y*8 + (seg_own-8) : -1; } \
        } }

    #define WRITE_FRAGS(AXT, V0, V1, V2, V3) {                                 \
        unsigned short tA_[8], tB_[8];                                         \
        _Pragma("unroll")                                                      \
        for (int j = 0; j < 4; j++) {                                          \
            tA_[j]   = f2bf(V0[j]); tA_[4+j] = f2bf(V1[j]);                    \
            tB_[j]   = f2bf(V2[j]); tB_[4+j] = f2bf(V3[j]);                    \
        }                                                                      \
        int k_ = seg_own*16;                                                   \
        int kk_ = k_ >> 5, ln_ = m_own + 16*((k_ >> 3) & 3);                   \
        *(short8v*)&AXT[(kk_*64 + ln_)*8] = *(short8v*)tA_;                    \
        k_ += 8; kk_ = k_ >> 5; ln_ = m_own + 16*((k_ >> 3) & 3);              \
        *(short8v*)&AXT[(kk_*64 + ln_)*8] = *(short8v*)tB_;                    \
    }

    // ---- level-0 gather (roots/slots: always ready) ----
    if (tid < 256) {
        const float* src; int f8; bool pad;
        RESOLVE(0, src, f8, pad);
        f32x4 z = (f32x4){0.f,0.f,0.f,0.f};
        f32x4 v0 = z, v1 = z, v2 = z, v3 = z;
        if (!pad) {
            const f32x4* s4 = (const f32x4*)src;
            v0 = s4[0]; v1 = s4[1]; v2 = s4[2]; v3 = s4[3];
        }
        WRITE_FRAGS(axFA, v0, v1, v2, v3);
    }
    // per-thread gather carry + flag snapshot for level 1
    const float* srcC = nullptr; int fiC = -1; bool padC = true; unsigned fvC = 1u;
    if (tid < 256) {
        RESOLVE(1, srcC, fiC, padC);
        if (!padC && fiC >= 0)
            fvC = __hip_atomic_load(&flags[fiC], __ATOMIC_RELAXED, __HIP_MEMORY_SCOPE_AGENT);
    }
    __syncthreads();

    unsigned short* axc = axFA;
    unsigned short* axn = axFB;

    for (int l = 0; l < LL; l++) {
        bool havN = (l + 1 < LL);

        // ---- phase A: row loads for snapshot-confirmed-ready parents ----
        bool pend = false; unsigned fv2 = 0u;
        f32x4 z = (f32x4){0.f,0.f,0.f,0.f};
        f32x4 v0 = z, v1 = z, v2 = z, v3 = z;
        if (havN && tid < 256 && !padC) {
            bool ready = (fiC < 0) || (fvC != 0u);
            if (ready) {
                asm volatile("" ::: "memory");
                const f32x4* s4 = (const f32x4*)srcC;
                v0 = s4[0]; v1 = s4[1]; v2 = s4[2]; v3 = s4[3];
            } else {
                pend = true;
                fv2 = __hip_atomic_load(&flags[fiC], __ATOMIC_RELAXED,
                                        __HIP_MEMORY_SCOPE_AGENT);
            }
        }
        __builtin_amdgcn_sched_barrier(0);   // pin: loads issued before compute

        int e = ech[l];
        if (e >= 0) {
            // ---- layer 1: H = GELU(X @ W1 + b1), weights in VGPRs ----
            f32x4 acc0 = (f32x4){b1v0, b1v0, b1v0, b1v0};
            f32x4 acc1 = (f32x4){b1v1, b1v1, b1v1, b1v1};
            {
                const short8v* Ab = (const short8v*)axc;
                #pragma unroll
                for (int kk = 0; kk < 8; kk++) {
                    short8v a = Ab[kk*64 + lq];
                    acc0 = __builtin_amdgcn_mfma_f32_16x16x32_bf16(a, w1r0[kk], acc0, 0, 0, 0);
                    acc1 = __builtin_amdgcn_mfma_f32_16x16x32_bf16(a, w1r1[kk], acc1, 0, 0, 0);
                }
            }
            // ---- mid-check: late flag arrived? issue row loads now (hidden) ----
            if (pend && fv2 != 0u) {
                asm volatile("" ::: "memory");
                const f32x4* s4 = (const f32x4*)srcC;
                v0 = s4[0]; v1 = s4[1]; v2 = s4[2]; v3 = s4[3];
                pend = false;
            }
            __builtin_amdgcn_sched_barrier(0);

            // GELU + scatter H into A-frag LDS (nt = 2w+c, c in {0,1})
            #pragma unroll
            for (int c = 0; c < 2; c++) {
                int nh = (2*w + c)*16 + (lq & 15);
                int kk2 = nh >> 5;
                int jj  = nh & 7;
                int lhi = 16*((nh >> 3) & 3);
                #pragma unroll
                for (int r = 0; r < 4; r++) {
                    int m = (lq >> 4)*4 + r;
                    float h = (c == 0) ? acc0[r] : acc1[r];
                    hxF[(kk2*64 + (m + lhi))*8 + jj] = f2bf(gelu_f(h));
                }
            }
            __syncthreads();

            // ---- layer 2: OUT = H @ W2 + b2 (nt = w) ----
            f32x4 acc2 = (f32x4){b2v, b2v, b2v, b2v};
            {
                const short8v* Hb = (const short8v*)hxF;
                #pragma unroll
                for (int kk = 0; kk < 8; kk++) {
                    short8v a = Hb[kk*64 + lq];
                    acc2 = __builtin_amdgcn_mfma_f32_16x16x32_bf16(a, w2r[kk], acc2, 0, 0, 0);
                }
            }
            // result rows: sc1 write-through to the coherence point
            int baserow = RR + l*MM;
            int n = w*16 + (lq & 15);
            #pragma unroll
            for (int r = 0; r < 4; r++) {
                int m = (lq >> 4)*4 + r;
                int node = descs[l][m].x;
                if (node >= 0)
                    __hip_atomic_store(&buf[(size_t)(baserow + node)*DD + n], acc2[r],
                                       __ATOMIC_RELAXED, __HIP_MEMORY_SCOPE_AGENT);
            }
            // per-wave drain (vmcnt is per-wave) -> publish THIS WAVE's flag
            asm volatile("s_waitcnt vmcnt(0)" ::: "memory");
            if ((tid & 63) == 0)
                __hip_atomic_store(&flags[(l*CCAP + wg)*8 + w], 1u, __ATOMIC_RELAXED,
                                   __HIP_MEMORY_SCOPE_AGENT);
        }

        // ---- snapshot issue for level l+2 (per-thread; consumed at bottom) ----
        const float* srcN = nullptr; int fiN = -1; bool padN = true; unsigned fvN = 1u;
        if (l + 2 < LL && tid < 256) {
            RESOLVE(l+2, srcN, fiN, padN);
            if (!padN && fiN >= 0)
                fvN = __hip_atomic_load(&flags[fiN], __ATOMIC_RELAXED,
                                        __HIP_MEMORY_SCOPE_AGENT);
        }

        // ---- phase B: spin only on genuine same-level (gate) parents ----
        if (havN && tid < 256) {
            if (pend) {
                while (__hip_atomic_load(&flags[fiC], __ATOMIC_RELAXED,
                                         __HIP_MEMORY_SCOPE_AGENT) == 0u)
                    __builtin_amdgcn_s_sleep(1);
                asm volatile("" ::: "memory");
                const f32x4* s4 = (const f32x4*)srcC;
                v0 = s4[0]; v1 = s4[1]; v2 = s4[2]; v3 = s4[3];
            }
            WRITE_FRAGS(axn, v0, v1, v2, v3);
        }

        __syncthreads();
        unsigned short* t2 = axc; axc = axn; axn = t2;
        srcC = srcN; fiC = fiN; padC = padN; fvC = fvN;
    }
}

extern "C" void kernel_launch(void* const* d_in, const int* in_sizes, int n_in,
                              void* d_out, int out_size, void* d_ws, size_t ws_size,
                              hipStream_t stream) {
    const float* root  = (const float*)d_in[0];   // (1024, 128)
    const float* W1    = (const float*)d_in[1];   // (5, 256, 256)
    const float* b1    = (const float*)d_in[2];   // (5, 256)
    const float* W2    = (const float*)d_in[3];   // (5, 256, 128)
    const float* b2    = (const float*)d_in[4];   // (5, 128)
    const float* slots = (const float*)d_in[5];   // (256, 128)
    const int*   par   = (const int*)d_in[6];     // (131072, 2)
    const int*   typ   = (const int*)d_in[7];     // (131072,)
    float* out = (float*)d_out;                   // (132096, 128)

    unsigned short* W1F     = (unsigned short*)d_ws;          // 327680 shorts
    unsigned short* W2F     = W1F + 5*16*8*64*8;              // 163840 shorts
    unsigned short* order   = W2F + 5*8*8*64*8;               // 64*2528 shorts
    unsigned char*  chunkof = (unsigned char*)(order + LL*PAD16);  // 131072 B
    unsigned int*   flags   = (unsigned int*)(chunkof + LL*MM);    // 64*158*8 u32

    // single fused prep dispatch (order/chunkof, weights, roots, flags)
    prep_all<<<LL + 240 + 32 + 40, 256, 0, stream>>>(root, W1, W2, typ, par, out,
                                                     W1F, W2F, order, chunkof, flags);

    // persistent dataflow sweep (co-residency guaranteed by cooperative launch)
    void* args[] = { (void*)&W1F, (void*)&W2F, (void*)&b1, (void*)&b2,
                     (void*)&slots, (void*)&par, (void*)&typ, (void*)&order,
                     (void*)&chunkof, (void*)&out, (void*)&flags };
    hipLaunchCooperativeKernel((const void*)persist_mfma, dim3(CH), dim3(512),
                               args, 0, stream);
}